// Round 10
// baseline (496.117 us; speedup 1.0000x reference)
//
#include <hip/hip_runtime.h>
#include <hip/hip_fp16.h>
#include <cstdint>

#define HIDDEN 128
#define MTOT 16
#define MAXT 10  // edges per group at harness sizes (E=1.6M, ngroups=160000)

typedef float vfloat4 __attribute__((ext_vector_type(4)));

// ---------------------------------------------------------------------------
// Zero-fill d_out (harness poisons d_out with 0xAA; graph must re-zero).
// ---------------------------------------------------------------------------
__global__ __launch_bounds__(256) void zero_kernel(float4* __restrict__ out,
                                                   int n4) {
  int i = blockIdx.x * 256 + threadIdx.x;
  int stride = gridDim.x * 256;
  float4 z = {0.f, 0.f, 0.f, 0.f};
  for (; i < n4; i += stride) out[i] = z;
}

// ---------------------------------------------------------------------------
// q/k projection, fp16 output. W in LDS, float4-preserving XOR swizzle.
// 8-row unroll: one ds_read_b128 feeds 32 FMAs.
// ---------------------------------------------------------------------------
__global__ __launch_bounds__(256) void proj_kernel(
    const float* __restrict__ x, const float* __restrict__ W,
    __half* __restrict__ out, int n_rows, float scale) {
  __shared__ float sW[128 * 128];  // 64 KB, swizzled
  for (int i = threadIdx.x; i < 128 * 128; i += 256) {
    int j = i >> 7, d = i & 127;
    sW[j * 128 + (d ^ ((j & 7) << 2))] = W[i] * scale;
  }
  __syncthreads();

  const int col = threadIdx.x & 127;
  const int g   = threadIdx.x >> 7;
  const int sx  = (col & 7) << 2;
  const float* sWc = sW + col * 128;

  const int row0 = blockIdx.x * 64;
#pragma unroll 1
  for (int m = 0; m < 4; ++m) {
    int r0 = row0 + g * 8 + m * 16;
    if (r0 >= n_rows) break;
    const float4* x4 = (const float4*)(x + (size_t)r0 * HIDDEN);
    if (r0 + 7 < n_rows) {
      float a0 = 0.f, a1 = 0.f, a2 = 0.f, a3 = 0.f;
      float a4 = 0.f, a5 = 0.f, a6 = 0.f, a7 = 0.f;
#pragma unroll
      for (int d4 = 0; d4 < 32; ++d4) {
        float4 w4 = *(const float4*)(sWc + ((d4 << 2) ^ sx));
        float4 xv0 = x4[d4];
        float4 xv1 = x4[32 + d4];
        float4 xv2 = x4[64 + d4];
        float4 xv3 = x4[96 + d4];
        float4 xv4 = x4[128 + d4];
        float4 xv5 = x4[160 + d4];
        float4 xv6 = x4[192 + d4];
        float4 xv7 = x4[224 + d4];
        a0 += xv0.x * w4.x + xv0.y * w4.y + xv0.z * w4.z + xv0.w * w4.w;
        a1 += xv1.x * w4.x + xv1.y * w4.y + xv1.z * w4.z + xv1.w * w4.w;
        a2 += xv2.x * w4.x + xv2.y * w4.y + xv2.z * w4.z + xv2.w * w4.w;
        a3 += xv3.x * w4.x + xv3.y * w4.y + xv3.z * w4.z + xv3.w * w4.w;
        a4 += xv4.x * w4.x + xv4.y * w4.y + xv4.z * w4.z + xv4.w * w4.w;
        a5 += xv5.x * w4.x + xv5.y * w4.y + xv5.z * w4.z + xv5.w * w4.w;
        a6 += xv6.x * w4.x + xv6.y * w4.y + xv6.z * w4.z + xv6.w * w4.w;
        a7 += xv7.x * w4.x + xv7.y * w4.y + xv7.z * w4.z + xv7.w * w4.w;
      }
      out[(size_t)(r0 + 0) * HIDDEN + col] = __float2half(a0);
      out[(size_t)(r0 + 1) * HIDDEN + col] = __float2half(a1);
      out[(size_t)(r0 + 2) * HIDDEN + col] = __float2half(a2);
      out[(size_t)(r0 + 3) * HIDDEN + col] = __float2half(a3);
      out[(size_t)(r0 + 4) * HIDDEN + col] = __float2half(a4);
      out[(size_t)(r0 + 5) * HIDDEN + col] = __float2half(a5);
      out[(size_t)(r0 + 6) * HIDDEN + col] = __float2half(a6);
      out[(size_t)(r0 + 7) * HIDDEN + col] = __float2half(a7);
    } else {
      for (int r = r0; r < n_rows; ++r) {
        const float4* xr = (const float4*)(x + (size_t)r * HIDDEN);
        float a = 0.f;
        for (int d4 = 0; d4 < 32; ++d4) {
          float4 w4 = *(const float4*)(sWc + ((d4 << 2) ^ sx));
          float4 xv = xr[d4];
          a += xv.x * w4.x + xv.y * w4.y + xv.z * w4.z + xv.w * w4.w;
        }
        out[(size_t)r * HIDDEN + col] = __float2half(a);
      }
    }
  }
}

// ---------------------------------------------------------------------------
// Edge kernel (R8 structure + full index preload).
// All 10 edge slots' (src,dst,cutoff) are loaded into registers UP FRONT
// (independent loads, one drain). The main loop then has register-ready
// gather addresses at iteration top -> no ei->gather dependent chain; the
// compiler can hoist iteration t+2's q/k/w loads under iteration t's compute.
// 2-edge unroll + XCD-contiguity swizzle + f32 atomics (R9 proved pk-f16 null).
// ---------------------------------------------------------------------------
__global__ __launch_bounds__(256) void edge_kernel(
    const __half* __restrict__ q, const __half* __restrict__ k,
    const float* __restrict__ w_ij, const float* __restrict__ sph,
    const int* __restrict__ ei, const float* __restrict__ cutoff,
    float* __restrict__ out, int E, int ngroups, int nb8) {
  const int rank     = (blockIdx.x & 7) * nb8 + (blockIdx.x >> 3);
  const int gid      = rank * 8 + (threadIdx.x >> 5);
  const int lane     = threadIdx.x & 31;
  const int halfbase = threadIdx.x & 32;
  // m -> head: m0->h0, m1..3->h1, m4..8->h2, m9..15->h3
  const int h_for_m  = (lane >= 1) + (lane >= 4) + (lane >= 9);
  const int srcLane  = halfbase + (h_for_m << 3);

  if (gid >= E) return;
  const int cnt = (E - 1 - gid) / ngroups + 1;  // == 10 at harness sizes

  // --- preload all edge indices/cutoffs into registers (static indexing) ---
  int srcs[MAXT], dsts[MAXT];
  float cuts[MAXT];
#pragma unroll
  for (int t = 0; t < MAXT; ++t) {
    if (t < cnt) {
      const int e = gid + t * ngroups;
      srcs[t] = __builtin_nontemporal_load(ei + e);
      dsts[t] = __builtin_nontemporal_load(ei + E + e);
      cuts[t] = __builtin_nontemporal_load(cutoff + e);
    }
  }

  // --- main loop: 2-edge unrolled, fully static ---
#pragma unroll
  for (int t = 0; t < MAXT; t += 2) {
    if (t + 1 < cnt) {
      const int eA = gid + t * ngroups;
      const int eB = eA + ngroups;
      vfloat4 wA = __builtin_nontemporal_load(
          (const vfloat4*)(w_ij + (size_t)eA * HIDDEN) + lane);
      vfloat4 wB = __builtin_nontemporal_load(
          (const vfloat4*)(w_ij + (size_t)eB * HIDDEN) + lane);
      union { uint2 u; __half2 h2[2]; } qA, kA, qB, kB;
      qA.u = *((const uint2*)(q + (size_t)dsts[t] * HIDDEN) + lane);
      kA.u = *((const uint2*)(k + (size_t)srcs[t] * HIDDEN) + lane);
      qB.u = *((const uint2*)(q + (size_t)dsts[t + 1] * HIDDEN) + lane);
      kB.u = *((const uint2*)(k + (size_t)srcs[t + 1] * HIDDEN) + lane);

      float2 qa01 = __half22float2(qA.h2[0]);
      float2 qa23 = __half22float2(qA.h2[1]);
      float2 ka01 = __half22float2(kA.h2[0]);
      float2 ka23 = __half22float2(kA.h2[1]);
      float pA = qa01.x * wA.x * ka01.x + qa01.y * wA.y * ka01.y +
                 qa23.x * wA.z * ka23.x + qa23.y * wA.w * ka23.y;
      float2 qb01 = __half22float2(qB.h2[0]);
      float2 qb23 = __half22float2(qB.h2[1]);
      float2 kb01 = __half22float2(kB.h2[0]);
      float2 kb23 = __half22float2(kB.h2[1]);
      float pB = qb01.x * wB.x * kb01.x + qb01.y * wB.y * kb01.y +
                 qb23.x * wB.z * kb23.x + qb23.y * wB.w * kb23.y;

      pA += __shfl_xor(pA, 1);
      pB += __shfl_xor(pB, 1);
      pA += __shfl_xor(pA, 2);
      pB += __shfl_xor(pB, 2);
      pA += __shfl_xor(pA, 4);
      pB += __shfl_xor(pB, 4);
      float alphaA = pA * cuts[t];
      float alphaB = pB * cuts[t + 1];
      float amA = __shfl(alphaA, srcLane);
      float amB = __shfl(alphaB, srcLane);
      if (lane < 16) {
        float sA = __builtin_nontemporal_load(sph + (size_t)eA * MTOT + lane);
        float sB = __builtin_nontemporal_load(sph + (size_t)eB * MTOT + lane);
        atomicAdd(out + (size_t)dsts[t] * MTOT + lane, amA * sA);
        atomicAdd(out + (size_t)dsts[t + 1] * MTOT + lane, amB * sB);
      }
    } else if (t < cnt) {  // odd tail within preloaded range
      const int eA = gid + t * ngroups;
      vfloat4 w4 = __builtin_nontemporal_load(
          (const vfloat4*)(w_ij + (size_t)eA * HIDDEN) + lane);
      union { uint2 u; __half2 h2[2]; } qa, ka;
      qa.u = *((const uint2*)(q + (size_t)dsts[t] * HIDDEN) + lane);
      ka.u = *((const uint2*)(k + (size_t)srcs[t] * HIDDEN) + lane);
      float2 q01 = __half22float2(qa.h2[0]);
      float2 q23 = __half22float2(qa.h2[1]);
      float2 k01 = __half22float2(ka.h2[0]);
      float2 k23 = __half22float2(ka.h2[1]);
      float p = q01.x * w4.x * k01.x + q01.y * w4.y * k01.y +
                q23.x * w4.z * k23.x + q23.y * w4.w * k23.y;
      p += __shfl_xor(p, 1);
      p += __shfl_xor(p, 2);
      p += __shfl_xor(p, 4);
      float alpha = p * cuts[t];
      float am = __shfl(alpha, srcLane);
      if (lane < 16) {
        float s = __builtin_nontemporal_load(sph + (size_t)eA * MTOT + lane);
        atomicAdd(out + (size_t)dsts[t] * MTOT + lane, am * s);
      }
    }
  }

  // safety: edges beyond MAXT per group (never taken at harness sizes)
  for (int t = MAXT; t < cnt; ++t) {
    const int e = gid + t * ngroups;
    int src = ei[e];
    int dst = ei[E + e];
    vfloat4 w4 = __builtin_nontemporal_load(
        (const vfloat4*)(w_ij + (size_t)e * HIDDEN) + lane);
    union { uint2 u; __half2 h2[2]; } qa, ka;
    qa.u = *((const uint2*)(q + (size_t)dst * HIDDEN) + lane);
    ka.u = *((const uint2*)(k + (size_t)src * HIDDEN) + lane);
    float2 q01 = __half22float2(qa.h2[0]);
    float2 q23 = __half22float2(qa.h2[1]);
    float2 k01 = __half22float2(ka.h2[0]);
    float2 k23 = __half22float2(ka.h2[1]);
    float p = q01.x * w4.x * k01.x + q01.y * w4.y * k01.y +
              q23.x * w4.z * k23.x + q23.y * w4.w * k23.y;
    p += __shfl_xor(p, 1);
    p += __shfl_xor(p, 2);
    p += __shfl_xor(p, 4);
    float alpha = p * cutoff[e];
    float am = __shfl(alpha, srcLane);
    if (lane < 16) {
      float s = sph[(size_t)e * MTOT + lane];
      atomicAdd(out + (size_t)dst * MTOT + lane, am * s);
    }
  }
}

extern "C" void kernel_launch(void* const* d_in, const int* in_sizes, int n_in,
                              void* d_out, int out_size, void* d_ws, size_t ws_size,
                              hipStream_t stream) {
  // inputs: chi, sph_ij, x, w_ij, edge_index, cutoff, Wq, Wk
  const float* sph    = (const float*)d_in[1];
  const float* x      = (const float*)d_in[2];
  const float* w_ij   = (const float*)d_in[3];
  const int*   ei     = (const int*)d_in[4];
  const float* cutoff = (const float*)d_in[5];
  const float* Wq     = (const float*)d_in[6];
  const float* Wk     = (const float*)d_in[7];
  float* out = (float*)d_out;

  const int n_nodes = in_sizes[0] / MTOT;  // chi is [N, 16]
  const int E       = in_sizes[5];         // cutoff is [E, 1]

  __half* q = (__half*)d_ws;
  __half* k = q + (size_t)n_nodes * HIDDEN;

  const int n4 = out_size / 4;
  zero_kernel<<<256, 256, 0, stream>>>((float4*)out, n4);

  const int pgrid = (n_nodes + 63) / 64;
  const float inv_sqrt_hd = 0.17677669529663687f;  // 1/sqrt(32)
  proj_kernel<<<pgrid, 256, 0, stream>>>(x, Wq, q, n_nodes, inv_sqrt_hd);
  proj_kernel<<<pgrid, 256, 0, stream>>>(x, Wk, k, n_nodes, 1.0f);

  const int NB = 20000;  // multiple of 8; 160000 groups, 10 edges each
  const int ngroups = NB * 8;
  edge_kernel<<<NB, 256, 0, stream>>>(q, k, w_ij, sph, ei, cutoff, out, E,
                                      ngroups, NB / 8);
}